// Round 10
// baseline (551.215 us; speedup 1.0000x reference)
//
#include <hip/hip_runtime.h>
#include <hip/hip_bf16.h>
#include <math.h>

typedef __attribute__((ext_vector_type(8))) short bf16x8;
typedef __attribute__((ext_vector_type(4))) short bf16x4;
typedef __attribute__((ext_vector_type(4))) float f32x4;

#define MM 8192   // B*S
#define CC 256

__device__ __forceinline__ short f2bf(float f) {
  unsigned u = __float_as_uint(f);
  u = (u + 0x7FFFu + ((u >> 16) & 1u)) >> 16;   // RNE
  return (short)u;
}

__device__ __forceinline__ void gload16(const short* g, short* l) {
  __builtin_amdgcn_global_load_lds(
      (const __attribute__((address_space(1))) unsigned int*)(g),
      (__attribute__((address_space(3))) unsigned int*)(l), 16, 0, 0);
}

// ================= halo-staged 3x3 dil=1 conv (dw / pw) =====================
// v3: THREE rotating W buffers (tap t -> buf t%3). issueW at tap t targets
// buf (t+2)%3 whose readers finished before tap t's barrier -> the post-
// compute barrier is gone: ONE barrier per tap + 1 per kc boundary (10/kc
// vs 18/kc in r5/r9). A single-buffered (written once per kc from regs).
// bn = bx&7 XCD swizzle keeps each 128-col W slice L2-resident.
// LDS = 3x8192 (W) + 12288 (A) shorts = 72 KB -> 2 blocks/CU.
__global__ __launch_bounds__(256, 2) void convh_k(const short* __restrict__ Ain,
                                                  const short* __restrict__ Wt,
                                                  short* __restrict__ outB,
                                                  const float* __restrict__ bias) {
  extern __shared__ short sm[];     // W0@0, W1@8192, W2@16384, A@24576 (12288)
  const int tid = threadIdx.x;
  const int bx = blockIdx.x;
  const int bm = bx >> 3, bn = bx & 7;   // W-affinity XCD swizzle
  const int l = tid & 63, w = tid >> 6;
  const int wm = w >> 1, wn = w & 1;
  const int lr = l & 15, lg = l >> 4;
  const int lsub = l >> 3;
  const int srcu = (l & 7) ^ lsub;
  const int img = bm >> 3, rbase = (bm & 7) * 4;
  const bf16x8 zv = {0, 0, 0, 0, 0, 0, 0, 0};
  short* const aBuf = sm + 24576;

  f32x4 acc[4][4];
#pragma unroll
  for (int i = 0; i < 4; ++i)
#pragma unroll
    for (int j = 0; j < 4; ++j) acc[i][j] = (f32x4){0.f, 0.f, 0.f, 0.f};

  const short* wsrc[4];
#pragma unroll
  for (int i = 0; i < 4; ++i) {
    int rowi = (w * 4 + i) * 8 + lsub;
    wsrc[i] = Wt + (size_t)(bn * 128 + rowi) * 1024 + srcu * 8;
  }

  // A halo staging geometry: 192 pos (6 rows x 32 px) x 8 units; 6 units/thread
  const short* asrc[6]; int apos[6]; bool avalid[6];
#pragma unroll
  for (int i = 0; i < 6; ++i) {
    int ug = tid + i * 256;
    int pos = ug >> 3, u = ug & 7;
    int irow = pos >> 5, px = pos & 31;
    int grow = rbase + irow - 1;
    avalid[i] = ((unsigned)grow < 32u);
    int growc = grow < 0 ? 0 : (grow > 31 ? 31 : grow);
    asrc[i] = Ain + ((size_t)(img * 1024 + growc * 32 + px)) * 1024 + u * 8;
    apos[i] = pos * 64 + ((u ^ (pos & 7)) << 3);
  }

  bf16x8 areg[6];
  auto issueA = [&](int kc) {
#pragma unroll
    for (int i = 0; i < 6; ++i)
      areg[i] = *(const bf16x8*)(asrc[i] + kc * 64);
  };
  auto writeA = [&]() {
#pragma unroll
    for (int i = 0; i < 6; ++i)
      *(bf16x8*)(aBuf + apos[i]) = avalid[i] ? areg[i] : zv;
  };
  auto issueW = [&](int kc, int tap, int wOff) {
    short* base = sm + wOff;
    size_t wo = (size_t)tap * 1048576 + (size_t)kc * 64;
#pragma unroll
    for (int i = 0; i < 4; ++i)
      gload16(wsrc[i] + wo, base + (w * 4 + i) * 512);
  };
  auto compute = [&](int dy, int dx, const short* bB) {
    __builtin_amdgcn_s_setprio(1);
#pragma unroll
    for (int ks = 0; ks < 64; ks += 32) {
      const int u = (ks >> 3) + lg;
      bf16x8 af[4], bfr[4];
#pragma unroll
      for (int mt = 0; mt < 4; ++mt) {
        int px = (mt & 1) * 16 + lr;
        int ipx = px + dx;
        bool okx = ((unsigned)ipx < 32u);
        int pos = (wm * 2 + (mt >> 1) + 1 + dy) * 32 + (ipx & 31);
        bf16x8 v = *(const bf16x8*)&aBuf[pos * 64 + ((u ^ (pos & 7)) << 3)];
        af[mt] = okx ? v : zv;
      }
#pragma unroll
      for (int nt = 0; nt < 4; ++nt)
        bfr[nt] = *(const bf16x8*)&bB[(wn * 64 + nt * 16 + lr) * 64 + ((u ^ (lr & 7)) << 3)];
#pragma unroll
      for (int mt = 0; mt < 4; ++mt)
#pragma unroll
        for (int nt = 0; nt < 4; ++nt)
          acc[mt][nt] = __builtin_amdgcn_mfma_f32_16x16x32_bf16(af[mt], bfr[nt], acc[mt][nt], 0, 0, 0);
    }
    __builtin_amdgcn_s_setprio(0);
  };

#define VM(n)  asm volatile("s_waitcnt vmcnt(" #n ")" ::: "memory")
#define BAR()  asm volatile("s_barrier" ::: "memory")

  // prologue: A(0) staged into LDS; W taps 0,1 of kc 0 in flight
  issueA(0);
  VM(0);
  writeA();
  issueW(0, 0, 0);
  issueW(0, 1, 8192);
  asm volatile("s_waitcnt lgkmcnt(0)" ::: "memory");

#pragma unroll 1
  for (int kc = 0; kc < 16; ++kc) {
    // tap 0 (buf0): operand issued 2 taps ago
    VM(4); BAR();
    compute(-1, -1, sm);
    if (kc < 15) issueA(kc + 1);            // 6 reg loads (older than tap0's W)
    issueW(kc, 2, 16384);
    // tap 1 (buf1): areg(6) + W@tap0(4) stay in flight
    if (kc < 15) { VM(10); } else { VM(4); }
    BAR();
    compute(-1, 0, sm + 8192);
    issueW(kc, 3, 0);
    // tap 2 (buf2): drains areg(6) + W@tap0(4)
    VM(4); BAR();
    compute(-1, 1, sm + 16384);
    issueW(kc, 4, 8192);
    // tap 3 (buf0)
    VM(4); BAR();
    compute(0, -1, sm);
    issueW(kc, 5, 16384);
    // tap 4 (buf1)
    VM(4); BAR();
    compute(0, 0, sm + 8192);
    issueW(kc, 6, 0);
    // tap 5 (buf2)
    VM(4); BAR();
    compute(0, 1, sm + 16384);
    issueW(kc, 7, 8192);
    // tap 6 (buf0)
    VM(4); BAR();
    compute(1, -1, sm);
    issueW(kc, 8, 16384);
    // tap 7 (buf1)
    VM(4); BAR();
    compute(1, 0, sm + 8192);
    if (kc < 15) issueW(kc + 1, 0, 0);
    // tap 8 (buf2)
    if (kc < 15) { VM(4); } else { VM(0); }
    BAR();
    compute(1, 1, sm + 16384);
    if (kc < 15) issueW(kc + 1, 1, 8192);
    // kc boundary: all waves done reading A -> rewrite it
    BAR();
    if (kc < 15) {
      writeA();
      asm volatile("s_waitcnt lgkmcnt(0)" ::: "memory");
    }
  }
#undef VM
#undef BAR

#pragma unroll
  for (int nt = 0; nt < 4; ++nt) {
    const int col = bn * 128 + wn * 64 + nt * 16 + lr;
    const float bi = bias[col];
#pragma unroll
    for (int mt = 0; mt < 4; ++mt) {
      const int row0 = bm * 128 + wm * 64 + mt * 16 + lg * 4;
#pragma unroll
      for (int j = 0; j < 4; ++j)
        outB[(size_t)(row0 + j) * 1024 + col] = f2bf(acc[mt][nt][j] + bi);
    }
  }
}

// ============== double-buffered pipelined GEMM (counted vmcnt) ==============
// HALF=0: BM=BN=128, 64KB LDS, grid (bm = bx&63, bn = bx>>6).
// HALF=1: BM=BN=64, 32KB LDS, N must be 256 (4 bn tiles): bm = bx>>2,
//         bn = bx&3 -> 512 blocks, fixes half-GPU-idle 128-block launches.
// TSTORE=1 additionally writes [B][C][S] f32 transposed (f32x4/lane).
struct GP {
  const short* A; const short* W; float* outF; short* outB; float* outT;
  const float* bias; const float* scale; const float* shift; const float* aux;
  const short* zero;
  long aZStride, wZStride, oZStride;
  int N, Kc, ldA, ldOut, outColOff, outZOff;
  int dil0, dil1, dil2, dil3;
  int T, nkcs;                   // T = TAPS*(Kc/64); nkcs = log2(Kc/64)
};

template<int TAPS, int EPI, int OUTMODE, int TSTORE, int HALF>
// EPI: 1=bias, 2=bias+gelu, 3=bias+relu+BN, 4=paGate, 5=BN+res
// OUTMODE: 0=f32, 1=bf16, 2=both, 3=none
__global__ __launch_bounds__(256, 2) void gemmd_k(GP p) {
  extern __shared__ short sm[];
  constexpr int RG   = HALF ? 2 : 4;      // 8-row groups staged per thread
  constexpr int MT   = HALF ? 2 : 4;
  constexpr int NT   = HALF ? 2 : 4;
  constexpr int WTs  = HALF ? 32 : 64;    // wave tile dim
  constexpr int BMr  = HALF ? 64 : 128;
  constexpr int BNr  = HALF ? 64 : 128;
  constexpr int BSTR = HALF ? 8192 : 16384;   // shorts per buffer
  constexpr int BOFF = HALF ? 4096 : 8192;    // B offset (shorts)
  const int tid = threadIdx.x;
  const int bx = blockIdx.x, bz = blockIdx.z;
  const int bm = HALF ? (bx >> 2) : (bx & 63);
  const int bn = HALF ? (bx & 3) : (bx >> 6);
  const int l = tid & 63, w = tid >> 6;
  const int wm = w >> 1, wn = w & 1;
  const int lr = l & 15, lg = l >> 4;
  const int lsub = l >> 3;
  const int srcu = (l & 7) ^ lsub;   // swizzled source 16B unit

  const short* Abase = p.A + (size_t)bz * p.aZStride;
  const short* Wbase = p.W + (size_t)bz * p.wZStride;
  const int dil = (TAPS == 9)
      ? (bz == 0 ? p.dil0 : bz == 1 ? p.dil1 : bz == 2 ? p.dil2 : p.dil3) : 1;

  f32x4 acc[MT][NT];
#pragma unroll
  for (int i = 0; i < MT; ++i)
#pragma unroll
    for (int j = 0; j < NT; ++j) acc[i][j] = (f32x4){0.f, 0.f, 0.f, 0.f};

  int rowi[RG], prow[RG], bimg[RG], py[RG], px[RG];
  const short* wsrc[RG];
#pragma unroll
  for (int i = 0; i < RG; ++i) {
    rowi[i] = (w * RG + i) * 8 + lsub;
    prow[i] = bm * BMr + rowi[i];
    bimg[i] = prow[i] >> 10; py[i] = (prow[i] >> 5) & 31; px[i] = prow[i] & 31;
    wsrc[i] = Wbase + (size_t)(bn * BNr + rowi[i]) * p.Kc + srcu * 8;
  }
  const size_t wTap = (size_t)p.N * p.Kc;
  const int nkcMask = (1 << p.nkcs) - 1;

  auto issue = [&](int t, int buf) {
    const int tap = t >> p.nkcs;
    const int kc = t & nkcMask;
    short* base = sm + buf * BSTR;
    if (TAPS == 1) {
#pragma unroll
      for (int i = 0; i < RG; ++i)
        gload16(Abase + (size_t)prow[i] * p.ldA + kc * 64 + srcu * 8,
                base + (w * RG + i) * 512);
    } else {
      const int dy = (tap / 3 - 1) * dil, dx = (tap % 3 - 1) * dil;
#pragma unroll
      for (int i = 0; i < RG; ++i) {
        int yy = py[i] + dy, xx = px[i] + dx;
        bool ok = ((unsigned)yy < 32u) & ((unsigned)xx < 32u);
        const short* a = ok
            ? Abase + (size_t)((bimg[i] << 10) + (yy << 5) + xx) * p.ldA + kc * 64
            : p.zero;
        gload16(a + srcu * 8, base + (w * RG + i) * 512);
      }
    }
    short* bbase = base + BOFF;
    const size_t wo = (size_t)tap * wTap + kc * 64;
#pragma unroll
    for (int i = 0; i < RG; ++i)
      gload16(wsrc[i] + wo, bbase + (w * RG + i) * 512);
  };

  auto compute = [&](int buf) {
    const short* bA = sm + buf * BSTR;
    const short* bB = bA + BOFF;
    __builtin_amdgcn_s_setprio(1);
#pragma unroll
    for (int ks = 0; ks < 64; ks += 32) {
      const int u = (ks >> 3) + lg;
      bf16x8 af[MT], bfr[NT];
#pragma unroll
      for (int mt = 0; mt < MT; ++mt)
        af[mt] = *(bf16x8*)&bA[(wm * WTs + mt * 16 + lr) * 64 + ((u ^ (lr & 7)) << 3)];
#pragma unroll
      for (int nt = 0; nt < NT; ++nt)
        bfr[nt] = *(bf16x8*)&bB[(wn * WTs + nt * 16 + lr) * 64 + ((u ^ (lr & 7)) << 3)];
#pragma unroll
      for (int mt = 0; mt < MT; ++mt)
#pragma unroll
        for (int nt = 0; nt < NT; ++nt)
          acc[mt][nt] = __builtin_amdgcn_mfma_f32_16x16x32_bf16(af[mt], bfr[nt], acc[mt][nt], 0, 0, 0);
    }
    __builtin_amdgcn_s_setprio(0);
  };

  issue(0, 0);
  if (p.T > 1) issue(1, 1);
  int cur = 0;
  for (int t = 0; t < p.T; ++t) {
    if (t + 1 < p.T) {
      if (HALF) asm volatile("s_waitcnt vmcnt(4)" ::: "memory");
      else      asm volatile("s_waitcnt vmcnt(8)" ::: "memory");
    } else {
      asm volatile("s_waitcnt vmcnt(0)" ::: "memory");
    }
    asm volatile("s_barrier" ::: "memory");
    compute(cur);
    asm volatile("s_barrier" ::: "memory");
    if (t + 2 < p.T) issue(t + 2, cur);
    cur ^= 1;
  }

  float* outF = p.outF + (size_t)bz * p.oZStride;
  short* outB = p.outB + (size_t)bz * p.oZStride;
#pragma unroll
  for (int nt = 0; nt < NT; ++nt) {
    const int col = bn * BNr + wn * WTs + nt * 16 + lr;
    const int gcol = p.outColOff + bz * p.outZOff + col;
    const float bi = (p.bias != nullptr) ? p.bias[bz * p.N + col] : 0.f;
    float scl = 0.f, shf = 0.f;
    if (EPI == 3 || EPI == 4 || EPI == 5) {
      scl = p.scale[bz * p.N + col]; shf = p.shift[bz * p.N + col];
    }
#pragma unroll
    for (int mt = 0; mt < MT; ++mt) {
      const int row0 = bm * BMr + wm * WTs + mt * 16 + lg * 4;
      f32x4 vv;
#pragma unroll
      for (int j = 0; j < 4; ++j) {
        const long row = row0 + j;
        float v = acc[mt][nt][j];
        if (EPI == 1 || EPI == 2 || EPI == 3) v += bi;
        if (EPI == 2) v = 0.5f * v * (1.f + erff(v * 0.70710678118654752f));   // exact gelu
        if (EPI == 3) { v = fmaxf(v, 0.f); v = v * scl + shf; }                // relu->BN
        if (EPI == 4) {                                                        // pa gate
          float t2 = v * scl + shf;
          float sg = 1.f / (1.f + __expf(-t2));
          v = p.aux[row * 256 + col] * sg;
        }
        if (EPI == 5) v = v * scl + shf + p.aux[row * 256 + col];              // BN+bias+mod_bias+x
        vv[j] = v;
        if (OUTMODE == 0 || OUTMODE == 2) outF[row * (long)p.ldOut + gcol] = v;
        if (OUTMODE == 1 || OUTMODE == 2) outB[row * (long)p.ldOut + gcol] = f2bf(v);
      }
      if (TSTORE) {   // [B][C][S] f32: lane's 4 rows are consecutive s
        float* t = p.outT + ((size_t)(row0 >> 10) * 256 + gcol) * 1024 + (row0 & 1023);
        *(f32x4*)t = vv;
      }
    }
  }
}

// ------------------------------------------------------------ attention -----
__global__ __launch_bounds__(256) void attn_k(const short* qb, const short* kb,
                                              const short* vb, short* ctx) {
  __shared__ short lK[128 * 40];
  __shared__ short lVt[32 * 136];
  __shared__ short lP[4][16 * 136];
  const int tid = threadIdx.x;
  const int qt = blockIdx.x;
  const int bh = blockIdx.y;
  const int b = bh >> 3, h = bh & 7;
  const int l = tid & 63, wv = tid >> 6;
  const int lr = l & 15, lg = l >> 4;
  const float SC = 0.17677669529663687f;

  const int qrow = qt * 64 + wv * 16 + lr;
  const bf16x8 qf = *(const bf16x8*)(qb + ((size_t)(b * 1024 + qrow)) * 256 + h * 32 + lg * 8);

  f32x4 o0 = {0.f,0.f,0.f,0.f}, o1 = {0.f,0.f,0.f,0.f};
  float m[4] = {-1e30f, -1e30f, -1e30f, -1e30f};
  float lsum[4] = {0.f, 0.f, 0.f, 0.f};

  for (int ch = 0; ch < 8; ++ch) {
    __syncthreads();
    {
      const int keyi = tid >> 1, d0 = (tid & 1) * 16;
      const short* src = kb + ((size_t)(b * 1024 + ch * 128 + keyi)) * 256 + h * 32 + d0;
      short* dst = &lK[keyi * 40 + d0];
      *(bf16x8*)dst = *(const bf16x8*)src;
      *(bf16x8*)(dst + 8) = *(const bf16x8*)(src + 8);
    }
    {
      const int keyi = tid >> 1, d0 = (tid & 1) * 16;
      const short* src = vb + ((size_t)(b * 1024 + ch * 128 + keyi)) * 256 + h * 32 + d0;
      short tmp[16];
      *(bf16x8*)tmp = *(const bf16x8*)src;
      *(bf16x8*)(tmp + 8) = *(const bf16x8*)(src + 8);
#pragma unroll
      for (int j = 0; j < 16; ++j) lVt[(d0 + j) * 136 + keyi] = tmp[j];
    }
    __syncthreads();

    f32x4 sc[8];
#pragma unroll
    for (int jt = 0; jt < 8; ++jt) {
      bf16x8 bfr = *(bf16x8*)&lK[(jt * 16 + lr) * 40 + lg * 8];
      sc[jt] = __builtin_amdgcn_mfma_f32_16x16x32_bf16(qf, bfr, (f32x4){0.f,0.f,0.f,0.f}, 0, 0, 0);
      sc[jt] *= SC;
    }
#pragma unroll
    for (int j = 0; j < 4; ++j) {
      float rm = -1e30f;
#pragma unroll
      for (int jt = 0; jt < 8; ++jt) rm = fmaxf(rm, sc[jt][j]);
      rm = fmaxf(rm, __shfl_xor(rm, 1));
      rm = fmaxf(rm, __shfl_xor(rm, 2));
      rm = fmaxf(rm, __shfl_xor(rm, 4));
      rm = fmaxf(rm, __shfl_xor(rm, 8));
      float mn = fmaxf(m[j], rm);
      float alpha = exp2f((m[j] - mn) * 1.44269504088896f);
      m[j] = mn;
      float rs = 0.f;
#pragma unroll
      for (int jt = 0; jt < 8; ++jt) {
        float pv = exp2f((sc[jt][j] - mn) * 1.44269504088896f);
        sc[jt][j] = pv;
        rs += pv;
      }
      rs += __shfl_xor(rs, 1); rs += __shfl_xor(rs, 2);
      rs += __shfl_xor(rs, 4); rs += __shfl_xor(rs, 8);
      lsum[j] = lsum[j] * alpha + rs;
      o0[j] *= alpha; o1[j] *= alpha;
      const int prw = lg * 4 + j;
#pragma unroll
      for (int jt = 0; jt < 8; ++jt) lP[wv][prw * 136 + jt * 16 + lr] = f2bf(sc[jt][j]);
    }
#pragma unroll
    for (int kc = 0; kc < 4; ++kc) {
      bf16x8 pf = *(bf16x8*)&lP[wv][lr * 136 + kc * 32 + lg * 8];
      bf16x8 v0 = *(bf16x8*)&lVt[lr * 136 + kc * 32 + lg * 8];
      bf16x8 v1 = *(bf16x8*)&lVt[(16 + lr) * 136 + kc * 32 + lg * 8];
      o0 = __builtin_amdgcn_mfma_f32_16x16x32_bf16(pf, v0, o0, 0, 0, 0);
      o1 = __builtin_amdgcn_mfma_f32_16x16x32_bf16(pf, v1, o1, 0, 0, 0);
    }
  }
  const size_t orow = (size_t)(b * 1024 + qt * 64 + wv * 16);
#pragma unroll
  for (int j = 0; j < 4; ++j) {
    float inv = 1.f / lsum[j];
    ctx[(orow + lg * 4 + j) * 256 + h * 32 + lr]      = f2bf(o0[j] * inv);
    ctx[(orow + lg * 4 + j) * 256 + h * 32 + 16 + lr] = f2bf(o1[j] * inv);
  }
}

// ------------------------------------------------------- small kernels ------
__global__ __launch_bounds__(256) void cvt4_k(const float* src, short* dst, int n4) {
  int i = blockIdx.x * 256 + threadIdx.x;
  if (i < n4) {
    f32x4 v = ((const f32x4*)src)[i];
    bf16x4 o;
    o[0] = f2bf(v[0]); o[1] = f2bf(v[1]); o[2] = f2bf(v[2]); o[3] = f2bf(v[3]);
    ((bf16x4*)dst)[i] = o;
  }
}

__global__ __launch_bounds__(256) void zero_k(short* p) {
  p[blockIdx.x * 256 + threadIdx.x] = 0;
}

// src [n][9] f32 -> dst [9][n] bf16
__global__ __launch_bounds__(256) void tap_k(const float* src, short* dst, int n) {
  int i = blockIdx.x * 256 + threadIdx.x;
  if (i >= n) return;
  const float* s = src + (size_t)i * 9;
  float v[9];
#pragma unroll
  for (int t = 0; t < 9; ++t) v[t] = s[t];
#pragma unroll
  for (int t = 0; t < 9; ++t) dst[(size_t)t * n + i] = f2bf(v[t]);
}

__global__ void bnprep_k(const float* pg, const float* pb, const float* pm, const float* pv,
                         const float* sg, const float* sb, const float* sm, const float* sv,
                         const float* og, const float* ob, const float* om, const float* ov,
                         const float* conv_ob, const float* mbias, float* out) {
  int c = threadIdx.x;
  float s = pg[c] / sqrtf(pv[c] + 1e-5f);
  out[c] = s;
  out[256 + c] = pb[c] - pm[c] * s;
  for (int i = 0; i < 4; ++i) {
    int idx = i * 256 + c;
    float ss = sg[idx] / sqrtf(sv[idx] + 1e-5f);
    out[512 + idx] = ss;
    out[1536 + idx] = sb[idx] - sm[idx] * ss;
  }
  float os = og[c] / sqrtf(ov[c] + 1e-5f);
  out[2560 + c] = os;
  out[2816 + c] = ob[c] - om[c] * os + conv_ob[c] * os + mbias[c];
}

// [B][C][S] f32 -> [B][S][C] bf16
__global__ __launch_bounds__(256) void tposeb_k(const float* src, short* dst) {
  __shared__ float tile[32][33];
  int pc = blockIdx.x, cc = blockIdx.y, b = blockIdx.z;
  int tx = threadIdx.x & 31, ty = threadIdx.x >> 5;
  const float* s = src + ((size_t)b * 256 + cc * 32) * 1024 + pc * 32;
#pragma unroll
  for (int k = 0; k < 4; ++k)
    tile[ty + 8 * k][tx] = s[(ty + 8 * k) * 1024 + tx];
  __syncthreads();
  short* d = dst + ((size_t)b * 1024 + pc * 32) * 256 + cc * 32;
#pragma unroll
  for (int k = 0; k < 4; ++k)
    d[(ty + 8 * k) * 256 + tx] = f2bf(tile[tx][ty + 8 * k]);
}

__global__ __launch_bounds__(256) void camean_k(const float* x, float* partial) {
  int blk = blockIdx.x, c = threadIdx.x;
  const float* px = x + ((size_t)blk * 64) * 256 + c;
  float s = 0.f;
#pragma unroll 4
  for (int r = 0; r < 64; ++r) s += px[(size_t)r * 256];
  partial[blk * 256 + c] = s;
}

__global__ __launch_bounds__(256) void ca2_k(const float* partial, const float* w1,
                                             const float* w2, float* y2) {
  __shared__ float ly[256];
  __shared__ float ly1[16];
  int b = blockIdx.x, c = threadIdx.x;
  float s = 0.f;
#pragma unroll
  for (int j = 0; j < 16; ++j) s += partial[(b * 16 + j) * 256 + c];
  ly[c] = s * (1.f / 1024.f);
  __syncthreads();
  if (c < 16) {
    float a = 0.f;
    const float* wp = w1 + c * 256;
    for (int i = 0; i < 256; ++i) a += ly[i] * wp[i];
    ly1[c] = fmaxf(a, 0.f);
  }
  __syncthreads();
  float a = 0.f;
  const float* wp = w2 + c * 16;
#pragma unroll
  for (int j = 0; j < 16; ++j) a += ly1[j] * wp[j];
  y2[b * 256 + c] = 1.f / (1.f + __expf(-a));
}

__global__ __launch_bounds__(256) void bm1_k(const float* paT, const float* xT,
                                             const float* y2, float* pa_ca) {
  __shared__ float sp[32][33], sx[32][33], so[32][33];
  __shared__ float rinv[32];
  int bc = blockIdx.x, t = threadIdx.x;
  for (int e = t; e < 1024; e += 256) {
    sp[e >> 5][e & 31] = paT[(size_t)bc * 1024 + e];
    sx[e >> 5][e & 31] = xT[(size_t)bc * 1024 + e];
  }
  __syncthreads();
  float yv = y2[bc];
  int i = t >> 3, j0 = (t & 7) * 4;
  float a0 = 0.f, a1 = 0.f, a2 = 0.f, a3 = 0.f;
  for (int k = 0; k < 32; ++k) {
    float pv = sp[i][k];
    a0 += pv * sx[k][j0];     a1 += pv * sx[k][j0 + 1];
    a2 += pv * sx[k][j0 + 2]; a3 += pv * sx[k][j0 + 3];
  }
  so[i][j0] = a0 * yv; so[i][j0 + 1] = a1 * yv;
  so[i][j0 + 2] = a2 * yv; so[i][j0 + 3] = a3 * yv;
  __syncthreads();
  if (t < 32) {
    float mx = -1e30f;
    for (int j = 0; j < 32; ++j) mx = fmaxf(mx, so[t][j]);
    float sum = 0.f;
    for (int j = 0; j < 32; ++j) { float pp = __expf(so[t][j] - mx); so[t][j] = pp; sum += pp; }
    rinv[t] = 1.f / sum;
  }
  __syncthreads();
  for (int e = t; e < 1024; e += 256)
    pa_ca[(size_t)bc * 1024 + e] = so[e >> 5][e & 31] * rinv[e >> 5];
}

__global__ __launch_bounds__(256) void bm2_k(const float* pa_ca, const float* saT, float* moT) {
  __shared__ float sp[32][33], ss[32][33];
  int bc = blockIdx.x, t = threadIdx.x;
  for (int e = t; e < 1024; e += 256) {
    sp[e >> 5][e & 31] = pa_ca[(size_t)bc * 1024 + e];
    ss[e >> 5][e & 31] = saT[(size_t)bc * 1024 + e];
  }
  __syncthreads();
  int i = t >> 3, j0 = (t & 7) * 4;
  float a0 = 0.f, a1 = 0.f, a2 = 0.f, a3 = 0.f;
  for (int k = 0; k < 32; ++k) {
    float pv = sp[i][k];
    a0 += pv * ss[k][j0];     a1 += pv * ss[k][j0 + 1];
    a2 += pv * ss[k][j0 + 2]; a3 += pv * ss[k][j0 + 3];
  }
  size_t base = (size_t)bc * 1024 + i * 32 + j0;
  moT[base] = a0; moT[base + 1] = a1; moT[base + 2] = a2; moT[base + 3] = a3;
}

template<int DUAL>
__global__ __launch_bounds__(256) void ln_k(const float* in, const float* res,
                                            const float* g, const float* bta,
                                            float* out, short* outB) {
  __shared__ float red[8];
  size_t row = blockIdx.x;
  int c = threadIdx.x;
  int wv = c >> 6, lane = c & 63;
  float v = in[row * 256 + c] + res[row * 256 + c];
  float s = v;
  for (int mk = 1; mk < 64; mk <<= 1) s += __shfl_xor(s, mk);
  if (lane == 0) red[wv] = s;
  __syncthreads();
  float mu = (red[0] + red[1] + red[2] + red[3]) * (1.f / 256.f);
  float d = v - mu;
  float q = d * d;
  for (int mk = 1; mk < 64; mk <<= 1) q += __shfl_xor(q, mk);
  if (lane == 0) red[4 + wv] = q;
  __syncthreads();
  float var = (red[4] + red[5] + red[6] + red[7]) * (1.f / 256.f);
  float o = d * rsqrtf(var + 1e-5f) * g[c] + bta[c];
  out[row * 256 + c] = o;
  if (DUAL) outB[row * 256 + c] = f2bf(o);
}

// ---------------------------------------------------------------- host ------
extern "C" void kernel_launch(void* const* d_in, const int* in_sizes, int n_in,
                              void* d_out, int out_size, void* d_ws, size_t ws_size,
                              hipStream_t stream) {
  (void)in_sizes; (void)n_in; (void)out_size; (void)ws_size;
  const float* value    = (const float*)d_in[0];
  const float* key      = (const float*)d_in[1];
  const float* query    = (const float*)d_in[2];
  const float* res      = (const float*)d_in[3];
  const float* attn_wi  = (const float*)d_in[4];
  const float* attn_bi  = (const float*)d_in[5];
  const float* attn_wo  = (const float*)d_in[6];
  const float* attn_bo  = (const float*)d_in[7];
  const float* mod_bias = (const float*)d_in[8];
  const float* ca_w1    = (const float*)d_in[9];
  const float* ca_w2    = (const float*)d_in[10];
  const float* pa_w     = (const float*)d_in[11];
  const float* pa_bn_g  = (const float*)d_in[12];
  const float* pa_bn_b  = (const float*)d_in[13];
  const float* pa_bn_m  = (const float*)d_in[14];
  const float* pa_bn_v  = (const float*)d_in[15];
  const float* sa_w     = (const float*)d_in[16];
  const float* sa_b     = (const float*)d_in[17];
  const float* sa_bn_g  = (const float*)d_in[18];
  const float* sa_bn_b  = (const float*)d_in[19];
  const float* sa_bn_m  = (const float*)d_in[20];
  const float* sa_bn_v  = (const float*)d_in[21];
  const float* sa_out_w = (const float*)d_in[22];
  const float* sa_out_b = (const float*)d_in[23];
  const float* out_w    = (const float*)d_in[24];
  const float* out_b    = (const float*)d_in[25];
  const float* out_bn_g = (const float*)d_in[26];
  const float* out_bn_b = (const float*)d_in[27];
  const float* out_bn_m = (const float*)d_in[28];
  const float* out_bn_v = (const float*)d_in[29];
  const float* ln1_g    = (const float*)d_in[30];
  const float* ln1_b    = (const float*)d_in[31];
  const float* ln2_g    = (const float*)d_in[32];
  const float* ln2_b    = (const float*)d_in[33];
  const float* mlp_w1   = (const float*)d_in[34];
  const float* mlp_b1   = (const float*)d_in[35];
  const float* dw_w     = (const float*)d_in[36];
  const float* dw_b     = (const float*)d_in[37];
  const float* pw_w     = (const float*)d_in[38];
  const float* pw_b     = (const float*)d_in[39];
  const float* mlp_w2   = (const float*)d_in[40];
  const float* mlp_b2   = (const float*)d_in[41];

  char* ws = (char*)d_ws;
  const size_t MB = 1024 * 1024;
  char* A = ws + 0 * MB;     // 16MB: vkq | xT+paT | saCat | h | h2
  char* Bx = ws + 16 * MB;   // 16MB: qkv | pa_ca | hc1
  char* Cx = ws + 32 * MB;   // 8MB:  ctxB | saT | modB | ffBuf
  float* xbuf  = (float*)(ws + 40 * MB);
  short* xbf   = (short*)(ws + 48 * MB);
  char* Fx = ws + 52 * MB;   // 8MB: moT | synBuf
  float* q2buf = (float*)(ws + 60 * MB);
  short* q2B   = (short*)(ws + 68 * MB);
  short* wdw   = (short*)(ws + 72 * MB);
  short* wpw   = (short*)(ws + 90 * MB);
  size_t o = 108 * MB;
  short* w_awi  = (short*)(ws + o); o += 768 * 256 * 2;
  short* w_awo  = (short*)(ws + o); o += 256 * 256 * 2;
  short* w_pa   = (short*)(ws + o); o += 256 * 256 * 2;
  short* w_sa   = (short*)(ws + o); o += (size_t)4 * 9 * 256 * 256 * 2;
  short* w_saou = (short*)(ws + o); o += 256 * 1024 * 2;
  short* w_out  = (short*)(ws + o); o += 256 * 256 * 2;
  short* w_mlp1 = (short*)(ws + o); o += 1024 * 256 * 2;
  short* w_mlp2 = (short*)(ws + o); o += 256 * 1024 * 2;
  float* bn     = (float*)(ws + o); o += 3072 * 4;
  float* y2buf  = (float*)(ws + o); o += 8 * 256 * 4;
  float* capart = (float*)(ws + o); o += 128 * 256 * 4;
  short* zbuf   = (short*)(ws + o); o += 2048 * 2;

  short* vkq  = (short*)A;
  short* qkv  = (short*)Bx;
  short* ctxB = (short*)Cx;
  float* xT   = (float*)A;
  float* paT  = (float*)(A + 8 * MB);
  float* pa_ca = (float*)Bx;
  short* saCat = (short*)A;
  float* saT  = (float*)Cx;
  float* moT  = (float*)Fx;
  short* modB = (short*)Cx;
  float* synBuf = (float*)Fx;
  short* hB   = (short*)A;
  short* hc1B = (short*)Bx;
  short* h2B  = (short*)A;
  float* ffBuf = (float*)Cx;

  const int LDSB = 2 * 16384 * 2;   // 64KB dynamic (full gemmd)
  const int LDSH = 2 * 8192 * 2;    // 32KB dynamic (HALF gemmd)
  const int LDSC = 36864 * 2;       // 72KB dynamic (convh v3)
  hipFuncSetAttribute((const void*)gemmd_k<1, 1, 1, 0, 1>, hipFuncAttributeMaxDynamicSharedMemorySize, LDSH);
  hipFuncSetAttribute((const void*)gemmd_k<1, 1, 2, 1, 1>, hipFuncAttributeMaxDynamicSharedMemorySize, LDSH);
  hipFuncSetAttribute((const void*)gemmd_k<1, 4, 3, 1, 1>, hipFuncAttributeMaxDynamicSharedMemorySize, LDSH);
  hipFuncSetAttribute((const void*)gemmd_k<9, 3, 1, 0, 0>, hipFuncAttributeMaxDynamicSharedMemorySize, LDSB);
  hipFuncSetAttribute((const void*)gemmd_k<1, 1, 3, 1, 1>, hipFuncAttributeMaxDynamicSharedMemorySize, LDSH);
  hipFuncSetAttribute((const void*)gemmd_k<1, 5, 0, 0, 1>, hipFuncAttributeMaxDynamicSharedMemorySize, LDSH);
  hipFuncSetAttribute((const void*)gemmd_k<1, 2, 1, 0, 0>, hipFuncAttributeMaxDynamicSharedMemorySize, LDSB);
  hipFuncSetAttribute((const void*)gemmd_k<1, 1, 0, 0, 1>, hipFuncAttributeMaxDynamicSharedMemorySize, LDSH);
  hipFuncSetAttribute((const void*)convh_k, hipFuncAttributeMaxDynamicSharedMemorySize, LDSC);

  // ---- prep ----
  zero_k<<<8, 256, 0, stream>>>(zbuf);
  cvt4_k<<<192, 256, 0, stream>>>(attn_wi, w_awi, 768 * 64);
  cvt4_k<<<64, 256, 0, stream>>>(attn_wo, w_awo, 256 * 64);
  cvt4_k<<<64, 256, 0, stream>>>(pa_w, w_pa, 256 * 64);
  for (int i4 = 0; i4 < 4; ++i4)
    tap_k<<<256, 256, 0, stream>>>(sa_w + (size_t)i4 * 589824,
                                   w_sa + (size_t)i4 * 589824, 65536);
  cvt4_k<<<256, 256, 0, stream>>>(sa_out_w, w_saou, 1024 * 64);
  cvt4_k<<<64, 256, 0, stream>>>(out_w, w_out, 256 * 64);
  cvt4_k<<<256, 256, 0, stream>>>(mlp_w1, w_mlp1, 1024 * 64);
  cvt4_k<<<256, 256, 0, stream>>>(mlp_w2, w_mlp2, 1024 * 64);
  tap_k<<<4096, 256, 0, stream>>>(dw_w, wdw, 1048576);
  tap_k<<<4096, 256, 0, stream>>>(pw_w, wpw, 1048576);
  bnprep_k<<<1, 256, 0, stream>>>(pa_bn_g, pa_bn_b, pa_bn_m, pa_bn_v,
                                  sa_bn_g, sa_bn_b, sa_bn_m, sa_bn_v,
                                  out_bn_g, out_bn_b, out_bn_m, out_bn_v,
                                  out_b, mod_bias, bn);
  cvt4_k<<<2048, 256, 0, stream>>>(value, vkq, MM * 64);
  cvt4_k<<<2048, 256, 0, stream>>>(key,   vkq + (size_t)MM * 256, MM * 64);
  cvt4_k<<<2048, 256, 0, stream>>>(query, vkq + (size_t)2 * MM * 256, MM * 64);

  GP g;
  g.zero = zbuf; g.scale = nullptr; g.shift = nullptr; g.aux = nullptr;
  g.aZStride = 0; g.wZStride = 0; g.oZStride = 0;
  g.outColOff = 0; g.outZOff = 0;
  g.dil0 = 1; g.dil1 = 1; g.dil2 = 1; g.dil3 = 1;
  g.outF = nullptr; g.outB = nullptr; g.outT = nullptr;

  // ---- QKV (z=0,1,2) (HALF: 512 blocks/z) ----
  g.A = vkq; g.W = w_awi; g.outB = qkv; g.bias = attn_bi;
  g.N = 256; g.Kc = 256; g.ldA = 256; g.ldOut = 256; g.T = 4; g.nkcs = 2;
  g.aZStride = (size_t)MM * 256; g.wZStride = 256 * 256; g.oZStride = (size_t)MM * 256;
  gemmd_k<1, 1, 1, 0, 1><<<dim3(512, 1, 3), 256, LDSH, stream>>>(g);
  g.aZStride = 0; g.wZStride = 0; g.oZStride = 0;

  // ---- attention ----
  attn_k<<<dim3(16, 64), 256, 0, stream>>>(qkv, qkv + (size_t)MM * 256,
                                           qkv + (size_t)2 * MM * 256, ctxB);

  // ---- out-proj -> xbuf(f32) + xbf(bf16) + xT(f32 transposed) ----
  g.A = ctxB; g.W = w_awo; g.outF = xbuf; g.outB = xbf; g.outT = xT; g.bias = attn_bo;
  gemmd_k<1, 1, 2, 1, 1><<<dim3(512), 256, LDSH, stream>>>(g);

  // ---- pa = x * sigmoid(BN(x @ pa_w^T)) -> paT (transposed only) ----
  g.A = xbf; g.W = w_pa; g.outF = nullptr; g.outB = nullptr; g.outT = paT; g.bias = nullptr;
  g.scale = bn; g.shift = bn + 256; g.aux = xbuf;
  gemmd_k<1, 4, 3, 1, 1><<<dim3(512), 256, LDSH, stream>>>(g);
  g.scale = nullptr; g.shift = nullptr; g.aux = nullptr;

  // ---- channel attention + pa@ca softmax ----
  camean_k<<<128, 256, 0, stream>>>(xbuf, capart);
  ca2_k<<<8, 256, 0, stream>>>(capart, ca_w1, ca_w2, y2buf);
  bm1_k<<<2048, 256, 0, stream>>>(paT, xT, y2buf, pa_ca);

  // ---- 4 dilated 3x3 convs (z-batched) -> saCat bf16 [M,1024] ----
  g.A = xbf; g.W = w_sa; g.outB = saCat; g.outF = nullptr; g.outT = nullptr;
  g.bias = sa_b; g.scale = bn + 512; g.shift = bn + 1536;
  g.ldOut = 1024; g.outZOff = 256; g.wZStride = (size_t)9 * 256 * 256;
  g.dil0 = 1; g.dil1 = 6; g.dil2 = 12; g.dil3 = 18;
  g.T = 36; g.nkcs = 2;
  gemmd_k<9, 3, 1, 0, 0><<<dim3(128, 1, 4), 256, LDSB, stream>>>(g);
  g.outZOff = 0; g.wZStride = 0; g.scale = nullptr; g.shift = nullptr;
  g.dil0 = 1; g.dil1 = 1; g.dil2 = 1; g.dil3 = 1;

  // ---- sa = saCat @ sa_out_w^T + b -> saT (transposed only) ----
  g.A = saCat; g.W = w_saou; g.outB = nullptr; g.outT = saT; g.bias = sa_out_b;
  g.N = 256; g.Kc = 1024; g.ldA = 1024; g.ldOut = 256; g.T = 16; g.nkcs = 4;
  gemmd_k<1, 1, 3, 1, 1><<<dim3(512), 256, LDSH, stream>>>(g);

  // ---- mod_out = pa_ca @ sa ----
  bm2_k<<<2048, 256, 0, stream>>>(pa_ca, saT, moT);
  tposeb_k<<<dim3(32, 8, 8), 256, 0, stream>>>(moT, modB);

  // ---- syn = BN(mod_out @ out_w^T + out_b) + mod_bias + x ----
  g.A = modB; g.W = w_out; g.outF = synBuf; g.outT = nullptr; g.bias = nullptr;
  g.scale = bn + 2560; g.shift = bn + 2816; g.aux = xbuf;
  g.N = 256; g.Kc = 256; g.ldA = 256; g.ldOut = 256; g.T = 4; g.nkcs = 2;
  gemmd_k<1, 5, 0, 0, 1><<<dim3(512), 256, LDSH, stream>>>(g);
  g.scale = nullptr; g.shift = nullptr; g.aux = nullptr;

  // ---- q2 = LN(syn + res) ----
  ln_k<1><<<8192, 256, 0, stream>>>(synBuf, res, ln1_g, ln1_b, q2buf, q2B);

  // ---- h = gelu(q2 @ mlp_w1^T + b1) ----
  g.A = q2B; g.W = w_mlp1; g.outB = hB; g.outF = nullptr; g.bias = mlp_b1;
  g.N = 1024; g.Kc = 256; g.ldA = 256; g.ldOut = 1024; g.T = 4; g.nkcs = 2;
  gemmd_k<1, 2, 1, 0, 0><<<dim3(512), 256, LDSB, stream>>>(g);

  // ---- hc1 = conv3x3(h, dw_w) + dw_b (convh v3) ----
  convh_k<<<dim3(512), 256, LDSC, stream>>>(hB, wdw, hc1B, dw_b);

  // ---- h2 = conv3x3(hc1, pw_w) + pw_b (convh v3) ----
  convh_k<<<dim3(512), 256, LDSC, stream>>>(hc1B, wpw, h2B, pw_b);

  // ---- ff = h2 @ mlp_w2^T + b2 ----
  g.A = h2B; g.W = w_mlp2; g.outF = ffBuf; g.outB = nullptr; g.bias = mlp_b2;
  g.N = 256; g.Kc = 1024; g.ldA = 1024; g.ldOut = 256; g.T = 16; g.nkcs = 4;
  gemmd_k<1, 1, 0, 0, 1><<<dim3(512), 256, LDSH, stream>>>(g);

  // ---- out = LN(ff + q2) ----
  ln_k<0><<<8192, 256, 0, stream>>>(ffBuf, q2buf, ln2_g, ln2_b, (float*)d_out, nullptr);
}

// Round 11
// 508.202 us; speedup vs baseline: 1.0846x; 1.0846x over previous
//
#include <hip/hip_runtime.h>
#include <hip/hip_bf16.h>
#include <math.h>

typedef __attribute__((ext_vector_type(8))) short bf16x8;
typedef __attribute__((ext_vector_type(4))) short bf16x4;
typedef __attribute__((ext_vector_type(4))) float f32x4;

#define MM 8192   // B*S
#define CC 256

__device__ __forceinline__ short f2bf(float f) {
  unsigned u = __float_as_uint(f);
  u = (u + 0x7FFFu + ((u >> 16) & 1u)) >> 16;   // RNE
  return (short)u;
}

__device__ __forceinline__ void gload16(const short* g, short* l) {
  __builtin_amdgcn_global_load_lds(
      (const __attribute__((address_space(1))) unsigned int*)(g),
      (__attribute__((address_space(3))) unsigned int*)(l), 16, 0, 0);
}

// ================= halo-staged 3x3 dil=1 conv (dw / pw) =====================
// r9 version (540.9us baseline): LDS-BW-bound at ~50% MfmaUtil -- structural
// plateau (barrier halving r10 = null; reg-W r6/r7 = VGPR spill). Keep.
// bn = bx&7 W-affinity XCD swizzle: 128-col W slice (2.36MB) L2-resident.
// LDS = 2x8192 (W) + 2x12288 (A) shorts = 80 KB -> 2 blocks/CU.
__global__ __launch_bounds__(256, 2) void convh_k(const short* __restrict__ Ain,
                                                  const short* __restrict__ Wt,
                                                  short* __restrict__ outB,
                                                  const float* __restrict__ bias) {
  extern __shared__ short sm[];     // W0 @0, W1 @8192, A0 @16384, A1 @28672
  const int tid = threadIdx.x;
  const int bx = blockIdx.x;
  const int bm = bx >> 3, bn = bx & 7;   // W-affinity XCD swizzle
  const int l = tid & 63, w = tid >> 6;
  const int wm = w >> 1, wn = w & 1;
  const int lr = l & 15, lg = l >> 4;
  const int lsub = l >> 3;
  const int srcu = (l & 7) ^ lsub;
  const int img = bm >> 3, rbase = (bm & 7) * 4;
  const bf16x8 zv = {0, 0, 0, 0, 0, 0, 0, 0};

  f32x4 acc[4][4];
#pragma unroll
  for (int i = 0; i < 4; ++i)
#pragma unroll
    for (int j = 0; j < 4; ++j) acc[i][j] = (f32x4){0.f, 0.f, 0.f, 0.f};

  const short* wsrc[4];
#pragma unroll
  for (int i = 0; i < 4; ++i) {
    int rowi = (w * 4 + i) * 8 + lsub;
    wsrc[i] = Wt + (size_t)(bn * 128 + rowi) * 1024 + srcu * 8;
  }

  // A halo staging geometry: 192 pos (6 rows x 32 px) x 8 units; 6 units/thread
  const short* asrc[6]; int apos[6]; bool avalid[6];
#pragma unroll
  for (int i = 0; i < 6; ++i) {
    int ug = tid + i * 256;
    int pos = ug >> 3, u = ug & 7;
    int irow = pos >> 5, px = pos & 31;
    int grow = rbase + irow - 1;
    avalid[i] = ((unsigned)grow < 32u);
    int growc = grow < 0 ? 0 : (grow > 31 ? 31 : grow);
    asrc[i] = Ain + ((size_t)(img * 1024 + growc * 32 + px)) * 1024 + u * 8;
    apos[i] = pos * 64 + ((u ^ (pos & 7)) << 3);
  }

  bf16x8 areg[6];
  auto issueA = [&](int kc) {
#pragma unroll
    for (int i = 0; i < 6; ++i)
      areg[i] = *(const bf16x8*)(asrc[i] + kc * 64);
  };
  auto writeA = [&](int ab) {
    short* abuf = sm + 16384 + ab * 12288;
#pragma unroll
    for (int i = 0; i < 6; ++i)
      *(bf16x8*)(abuf + apos[i]) = avalid[i] ? areg[i] : zv;
  };
  auto issueW = [&](int kc, int tap, int wb) {
    short* base = sm + wb * 8192;
    size_t wo = (size_t)tap * 1048576 + (size_t)kc * 64;
#pragma unroll
    for (int i = 0; i < 4; ++i)
      gload16(wsrc[i] + wo, base + (w * 4 + i) * 512);
  };
  auto compute = [&](int dy, int dx, const short* bA, const short* bB) {
    __builtin_amdgcn_s_setprio(1);
#pragma unroll
    for (int ks = 0; ks < 64; ks += 32) {
      const int u = (ks >> 3) + lg;
      bf16x8 af[4], bfr[4];
#pragma unroll
      for (int mt = 0; mt < 4; ++mt) {
        int px = (mt & 1) * 16 + lr;
        int ipx = px + dx;
        bool okx = ((unsigned)ipx < 32u);
        int pos = (wm * 2 + (mt >> 1) + 1 + dy) * 32 + (ipx & 31);
        bf16x8 v = *(const bf16x8*)&bA[pos * 64 + ((u ^ (pos & 7)) << 3)];
        af[mt] = okx ? v : zv;
      }
#pragma unroll
      for (int nt = 0; nt < 4; ++nt)
        bfr[nt] = *(const bf16x8*)&bB[(wn * 64 + nt * 16 + lr) * 64 + ((u ^ (lr & 7)) << 3)];
#pragma unroll
      for (int mt = 0; mt < 4; ++mt)
#pragma unroll
        for (int nt = 0; nt < 4; ++nt)
          acc[mt][nt] = __builtin_amdgcn_mfma_f32_16x16x32_bf16(af[mt], bfr[nt], acc[mt][nt], 0, 0, 0);
    }
    __builtin_amdgcn_s_setprio(0);
  };

  // prologue
  issueA(0);
  issueW(0, 0, 0);
  issueW(0, 1, 1);
  asm volatile("s_waitcnt vmcnt(4)" ::: "memory");   // A regs + W(0,0) done
  writeA(0);
  asm volatile("s_waitcnt lgkmcnt(0)" ::: "memory");

  for (int kc = 0; kc < 16; ++kc) {
    const int ab = kc & 1;
    const short* bA = sm + 16384 + ab * 12288;
#pragma unroll
    for (int tap = 0; tap < 9; ++tap) {
      const int wb = (kc + tap) & 1;
      const short* bB = sm + wb * 8192;
      if (tap == 7) {
        if (kc < 15) asm volatile("s_waitcnt vmcnt(10)" ::: "memory");
        else         asm volatile("s_waitcnt vmcnt(4)" ::: "memory");
      } else if (tap == 8) {
        if (kc < 15) asm volatile("s_waitcnt vmcnt(4)" ::: "memory");
        else         asm volatile("s_waitcnt vmcnt(0)" ::: "memory");
      } else {
        asm volatile("s_waitcnt vmcnt(4)" ::: "memory");
      }
      asm volatile("s_barrier" ::: "memory");
      compute(tap / 3 - 1, tap % 3 - 1, bA, bB);
      asm volatile("s_barrier" ::: "memory");
      if (tap <= 6) {
        if (tap == 6 && kc < 15) issueA(kc + 1);
        issueW(kc, tap + 2, wb);
      } else if (tap == 7) {
        if (kc < 15) issueW(kc + 1, 0, wb);
      } else {
        if (kc < 15) {
          writeA(ab ^ 1);
          asm volatile("s_waitcnt lgkmcnt(0)" ::: "memory");
          issueW(kc + 1, 1, wb);
        }
      }
    }
  }

#pragma unroll
  for (int nt = 0; nt < 4; ++nt) {
    const int col = bn * 128 + wn * 64 + nt * 16 + lr;
    const float bi = bias[col];
#pragma unroll
    for (int mt = 0; mt < 4; ++mt) {
      const int row0 = bm * 128 + wm * 64 + mt * 16 + lg * 4;
#pragma unroll
      for (int j = 0; j < 4; ++j)
        outB[(size_t)(row0 + j) * 1024 + col] = f2bf(acc[mt][nt][j] + bi);
    }
  }
}

// ============== double-buffered pipelined GEMM (counted vmcnt) ==============
// HALF=0: BM=BN=128, 64KB LDS, grid (bm = bx&63, bn = bx>>6).
// HALF=1: BM=BN=64, 32KB LDS, N must be 256 (4 bn tiles): bm = bx>>2,
//         bn = bx&3 -> 512 blocks. TSTORE=1 also writes [B][C][S] f32.
struct GP {
  const short* A; const short* W; float* outF; short* outB; float* outT;
  const float* bias; const float* scale; const float* shift; const float* aux;
  const short* zero;
  long aZStride, wZStride, oZStride;
  int N, Kc, ldA, ldOut, outColOff, outZOff;
  int dil0, dil1, dil2, dil3;
  int T, nkcs;                   // T = TAPS*(Kc/64); nkcs = log2(Kc/64)
};

template<int TAPS, int EPI, int OUTMODE, int TSTORE, int HALF>
// EPI: 1=bias, 2=bias+gelu, 3=bias+relu+BN, 4=paGate, 5=BN+res
// OUTMODE: 0=f32, 1=bf16, 2=both, 3=none
__global__ __launch_bounds__(256, 2) void gemmd_k(GP p) {
  extern __shared__ short sm[];
  constexpr int RG   = HALF ? 2 : 4;
  constexpr int MT   = HALF ? 2 : 4;
  constexpr int NT   = HALF ? 2 : 4;
  constexpr int WTs  = HALF ? 32 : 64;
  constexpr int BMr  = HALF ? 64 : 128;
  constexpr int BNr  = HALF ? 64 : 128;
  constexpr int BSTR = HALF ? 8192 : 16384;
  constexpr int BOFF = HALF ? 4096 : 8192;
  const int tid = threadIdx.x;
  const int bx = blockIdx.x, bz = blockIdx.z;
  const int bm = HALF ? (bx >> 2) : (bx & 63);
  const int bn = HALF ? (bx & 3) : (bx >> 6);
  const int l = tid & 63, w = tid >> 6;
  const int wm = w >> 1, wn = w & 1;
  const int lr = l & 15, lg = l >> 4;
  const int lsub = l >> 3;
  const int srcu = (l & 7) ^ lsub;

  const short* Abase = p.A + (size_t)bz * p.aZStride;
  const short* Wbase = p.W + (size_t)bz * p.wZStride;
  const int dil = (TAPS == 9)
      ? (bz == 0 ? p.dil0 : bz == 1 ? p.dil1 : bz == 2 ? p.dil2 : p.dil3) : 1;

  f32x4 acc[MT][NT];
#pragma unroll
  for (int i = 0; i < MT; ++i)
#pragma unroll
    for (int j = 0; j < NT; ++j) acc[i][j] = (f32x4){0.f, 0.f, 0.f, 0.f};

  int rowi[RG], prow[RG], bimg[RG], py[RG], px[RG];
  const short* wsrc[RG];
#pragma unroll
  for (int i = 0; i < RG; ++i) {
    rowi[i] = (w * RG + i) * 8 + lsub;
    prow[i] = bm * BMr + rowi[i];
    bimg[i] = prow[i] >> 10; py[i] = (prow[i] >> 5) & 31; px[i] = prow[i] & 31;
    wsrc[i] = Wbase + (size_t)(bn * BNr + rowi[i]) * p.Kc + srcu * 8;
  }
  const size_t wTap = (size_t)p.N * p.Kc;
  const int nkcMask = (1 << p.nkcs) - 1;

  auto issue = [&](int t, int buf) {
    const int tap = t >> p.nkcs;
    const int kc = t & nkcMask;
    short* base = sm + buf * BSTR;
    if (TAPS == 1) {
#pragma unroll
      for (int i = 0; i < RG; ++i)
        gload16(Abase + (size_t)prow[i] * p.ldA + kc * 64 + srcu * 8,
                base + (w * RG + i) * 512);
    } else {
      const int dy = (tap / 3 - 1) * dil, dx = (tap % 3 - 1) * dil;
#pragma unroll
      for (int i = 0; i < RG; ++i) {
        int yy = py[i] + dy, xx = px[i] + dx;
        bool ok = ((unsigned)yy < 32u) & ((unsigned)xx < 32u);
        const short* a = ok
            ? Abase + (size_t)((bimg[i] << 10) + (yy << 5) + xx) * p.ldA + kc * 64
            : p.zero;
        gload16(a + srcu * 8, base + (w * RG + i) * 512);
      }
    }
    short* bbase = base + BOFF;
    const size_t wo = (size_t)tap * wTap + kc * 64;
#pragma unroll
    for (int i = 0; i < RG; ++i)
      gload16(wsrc[i] + wo, bbase + (w * RG + i) * 512);
  };

  auto compute = [&](int buf) {
    const short* bA = sm + buf * BSTR;
    const short* bB = bA + BOFF;
    __builtin_amdgcn_s_setprio(1);
#pragma unroll
    for (int ks = 0; ks < 64; ks += 32) {
      const int u = (ks >> 3) + lg;
      bf16x8 af[MT], bfr[NT];
#pragma unroll
      for (int mt = 0; mt < MT; ++mt)
        af[mt] = *(bf16x8*)&bA[(wm * WTs + mt * 16 + lr) * 64 + ((u ^ (lr & 7)) << 3)];
#pragma unroll
      for (int nt = 0; nt < NT; ++nt)
        bfr[nt] = *(bf16x8*)&bB[(wn * WTs + nt * 16 + lr) * 64 + ((u ^ (lr & 7)) << 3)];
#pragma unroll
      for (int mt = 0; mt < MT; ++mt)
#pragma unroll
        for (int nt = 0; nt < NT; ++nt)
          acc[mt][nt] = __builtin_amdgcn_mfma_f32_16x16x32_bf16(af[mt], bfr[nt], acc[mt][nt], 0, 0, 0);
    }
    __builtin_amdgcn_s_setprio(0);
  };

  issue(0, 0);
  if (p.T > 1) issue(1, 1);
  int cur = 0;
  for (int t = 0; t < p.T; ++t) {
    if (t + 1 < p.T) {
      if (HALF) asm volatile("s_waitcnt vmcnt(4)" ::: "memory");
      else      asm volatile("s_waitcnt vmcnt(8)" ::: "memory");
    } else {
      asm volatile("s_waitcnt vmcnt(0)" ::: "memory");
    }
    asm volatile("s_barrier" ::: "memory");
    compute(cur);
    asm volatile("s_barrier" ::: "memory");
    if (t + 2 < p.T) issue(t + 2, cur);
    cur ^= 1;
  }

  float* outF = p.outF + (size_t)bz * p.oZStride;
  short* outB = p.outB + (size_t)bz * p.oZStride;
#pragma unroll
  for (int nt = 0; nt < NT; ++nt) {
    const int col = bn * BNr + wn * WTs + nt * 16 + lr;
    const int gcol = p.outColOff + bz * p.outZOff + col;
    const float bi = (p.bias != nullptr) ? p.bias[bz * p.N + col] : 0.f;
    float scl = 0.f, shf = 0.f;
    if (EPI == 3 || EPI == 4 || EPI == 5) {
      scl = p.scale[bz * p.N + col]; shf = p.shift[bz * p.N + col];
    }
#pragma unroll
    for (int mt = 0; mt < MT; ++mt) {
      const int row0 = bm * BMr + wm * WTs + mt * 16 + lg * 4;
      f32x4 vv;
#pragma unroll
      for (int j = 0; j < 4; ++j) {
        const long row = row0 + j;
        float v = acc[mt][nt][j];
        if (EPI == 1 || EPI == 2 || EPI == 3) v += bi;
        if (EPI == 2) v = 0.5f * v * (1.f + erff(v * 0.70710678118654752f));   // exact gelu
        if (EPI == 3) { v = fmaxf(v, 0.f); v = v * scl + shf; }                // relu->BN
        if (EPI == 4) {                                                        // pa gate
          float t2 = v * scl + shf;
          float sg = 1.f / (1.f + __expf(-t2));
          v = p.aux[row * 256 + col] * sg;
        }
        if (EPI == 5) v = v * scl + shf + p.aux[row * 256 + col];              // BN+bias+mod_bias+x
        vv[j] = v;
        if (OUTMODE == 0 || OUTMODE == 2) outF[row * (long)p.ldOut + gcol] = v;
        if (OUTMODE == 1 || OUTMODE == 2) outB[row * (long)p.ldOut + gcol] = f2bf(v);
      }
      if (TSTORE) {
        float* t = p.outT + ((size_t)(row0 >> 10) * 256 + gcol) * 1024 + (row0 & 1023);
        *(f32x4*)t = vv;
      }
    }
  }
}

// ------------------------------------------------------------ attention -----
__global__ __launch_bounds__(256) void attn_k(const short* qb, const short* kb,
                                              const short* vb, short* ctx) {
  __shared__ short lK[128 * 40];
  __shared__ short lVt[32 * 136];
  __shared__ short lP[4][16 * 136];
  const int tid = threadIdx.x;
  const int qt = blockIdx.x;
  const int bh = blockIdx.y;
  const int b = bh >> 3, h = bh & 7;
  const int l = tid & 63, wv = tid >> 6;
  const int lr = l & 15, lg = l >> 4;
  const float SC = 0.17677669529663687f;

  const int qrow = qt * 64 + wv * 16 + lr;
  const bf16x8 qf = *(const bf16x8*)(qb + ((size_t)(b * 1024 + qrow)) * 256 + h * 32 + lg * 8);

  f32x4 o0 = {0.f,0.f,0.f,0.f}, o1 = {0.f,0.f,0.f,0.f};
  float m[4] = {-1e30f, -1e30f, -1e30f, -1e30f};
  float lsum[4] = {0.f, 0.f, 0.f, 0.f};

  for (int ch = 0; ch < 8; ++ch) {
    __syncthreads();
    {
      const int keyi = tid >> 1, d0 = (tid & 1) * 16;
      const short* src = kb + ((size_t)(b * 1024 + ch * 128 + keyi)) * 256 + h * 32 + d0;
      short* dst = &lK[keyi * 40 + d0];
      *(bf16x8*)dst = *(const bf16x8*)src;
      *(bf16x8*)(dst + 8) = *(const bf16x8*)(src + 8);
    }
    {
      const int keyi = tid >> 1, d0 = (tid & 1) * 16;
      const short* src = vb + ((size_t)(b * 1024 + ch * 128 + keyi)) * 256 + h * 32 + d0;
      short tmp[16];
      *(bf16x8*)tmp = *(const bf16x8*)src;
      *(bf16x8*)(tmp + 8) = *(const bf16x8*)(src + 8);
#pragma unroll
      for (int j = 0; j < 16; ++j) lVt[(d0 + j) * 136 + keyi] = tmp[j];
    }
    __syncthreads();

    f32x4 sc[8];
#pragma unroll
    for (int jt = 0; jt < 8; ++jt) {
      bf16x8 bfr = *(bf16x8*)&lK[(jt * 16 + lr) * 40 + lg * 8];
      sc[jt] = __builtin_amdgcn_mfma_f32_16x16x32_bf16(qf, bfr, (f32x4){0.f,0.f,0.f,0.f}, 0, 0, 0);
      sc[jt] *= SC;
    }
#pragma unroll
    for (int j = 0; j < 4; ++j) {
      float rm = -1e30f;
#pragma unroll
      for (int jt = 0; jt < 8; ++jt) rm = fmaxf(rm, sc[jt][j]);
      rm = fmaxf(rm, __shfl_xor(rm, 1));
      rm = fmaxf(rm, __shfl_xor(rm, 2));
      rm = fmaxf(rm, __shfl_xor(rm, 4));
      rm = fmaxf(rm, __shfl_xor(rm, 8));
      float mn = fmaxf(m[j], rm);
      float alpha = exp2f((m[j] - mn) * 1.44269504088896f);
      m[j] = mn;
      float rs = 0.f;
#pragma unroll
      for (int jt = 0; jt < 8; ++jt) {
        float pv = exp2f((sc[jt][j] - mn) * 1.44269504088896f);
        sc[jt][j] = pv;
        rs += pv;
      }
      rs += __shfl_xor(rs, 1); rs += __shfl_xor(rs, 2);
      rs += __shfl_xor(rs, 4); rs += __shfl_xor(rs, 8);
      lsum[j] = lsum[j] * alpha + rs;
      o0[j] *= alpha; o1[j] *= alpha;
      const int prw = lg * 4 + j;
#pragma unroll
      for (int jt = 0; jt < 8; ++jt) lP[wv][prw * 136 + jt * 16 + lr] = f2bf(sc[jt][j]);
    }
#pragma unroll
    for (int kc = 0; kc < 4; ++kc) {
      bf16x8 pf = *(bf16x8*)&lP[wv][lr * 136 + kc * 32 + lg * 8];
      bf16x8 v0 = *(bf16x8*)&lVt[lr * 136 + kc * 32 + lg * 8];
      bf16x8 v1 = *(bf16x8*)&lVt[(16 + lr) * 136 + kc * 32 + lg * 8];
      o0 = __builtin_amdgcn_mfma_f32_16x16x32_bf16(pf, v0, o0, 0, 0, 0);
      o1 = __builtin_amdgcn_mfma_f32_16x16x32_bf16(pf, v1, o1, 0, 0, 0);
    }
  }
  const size_t orow = (size_t)(b * 1024 + qt * 64 + wv * 16);
#pragma unroll
  for (int j = 0; j < 4; ++j) {
    float inv = 1.f / lsum[j];
    ctx[(orow + lg * 4 + j) * 256 + h * 32 + lr]      = f2bf(o0[j] * inv);
    ctx[(orow + lg * 4 + j) * 256 + h * 32 + 16 + lr] = f2bf(o1[j] * inv);
  }
}

// ===================== fused prep (replaces 18 small launches) ==============
struct PP {
  const float* value; const float* key; const float* query;
  const float* attn_wi; const float* attn_wo; const float* pa_w;
  const float* sa_out_w; const float* out_w; const float* mlp_w1; const float* mlp_w2;
  const float* sa_w; const float* dw_w; const float* pw_w;
  short* vkq; short* w_awi; short* w_awo; short* w_pa; short* w_saou;
  short* w_out; short* w_mlp1; short* w_mlp2; short* w_sa; short* wdw; short* wpw;
  short* zbuf;
  const float* pg; const float* pb; const float* pm; const float* pv;
  const float* sg; const float* sb; const float* smean; const float* svar;
  const float* og; const float* ob; const float* om; const float* ov;
  const float* conv_ob; const float* mbias; float* bn;
};

__global__ __launch_bounds__(256) void prep_k(PP p) {
  const int b = blockIdx.x, t = threadIdx.x;
  auto cvt = [&](const float* s, short* d, int b0) {
    int i = (b - b0) * 256 + t;
    f32x4 v = ((const f32x4*)s)[i];
    bf16x4 o;
    o[0] = f2bf(v[0]); o[1] = f2bf(v[1]); o[2] = f2bf(v[2]); o[3] = f2bf(v[3]);
    ((bf16x4*)d)[i] = o;
  };
  auto tap = [&](const float* s, short* d, int n, int b0) {
    int i = (b - b0) * 256 + t;
    if (i >= n) return;
    const float* sp = s + (size_t)i * 9;
    float v[9];
#pragma unroll
    for (int k = 0; k < 9; ++k) v[k] = sp[k];
#pragma unroll
    for (int k = 0; k < 9; ++k) d[(size_t)k * n + i] = f2bf(v[k]);
  };
  if (b < 2048)        cvt(p.value, p.vkq, 0);
  else if (b < 4096)   cvt(p.key,   p.vkq + (size_t)MM * 256, 2048);
  else if (b < 6144)   cvt(p.query, p.vkq + (size_t)2 * MM * 256, 4096);
  else if (b < 6336)   cvt(p.attn_wi,  p.w_awi, 6144);
  else if (b < 6400)   cvt(p.attn_wo,  p.w_awo, 6336);
  else if (b < 6464)   cvt(p.pa_w,     p.w_pa, 6400);
  else if (b < 6720)   cvt(p.sa_out_w, p.w_saou, 6464);
  else if (b < 6784)   cvt(p.out_w,    p.w_out, 6720);
  else if (b < 7040)   cvt(p.mlp_w1,   p.w_mlp1, 6784);
  else if (b < 7296)   cvt(p.mlp_w2,   p.w_mlp2, 7040);
  else if (b < 8320) {
    int i4 = (b - 7296) >> 8;
    tap(p.sa_w + (size_t)i4 * 589824, p.w_sa + (size_t)i4 * 589824, 65536,
        7296 + i4 * 256);
  }
  else if (b < 12416)  tap(p.dw_w, p.wdw, 1048576, 8320);
  else if (b < 16512)  tap(p.pw_w, p.wpw, 1048576, 12416);
  else if (b == 16512) {
#pragma unroll
    for (int j = 0; j < 8; ++j) p.zbuf[t * 8 + j] = 0;
  } else {   // bnprep (1 block)
    int c = t;
    float s = p.pg[c] / sqrtf(p.pv[c] + 1e-5f);
    p.bn[c] = s;
    p.bn[256 + c] = p.pb[c] - p.pm[c] * s;
    for (int i = 0; i < 4; ++i) {
      int idx = i * 256 + c;
      float ss = p.sg[idx] / sqrtf(p.svar[idx] + 1e-5f);
      p.bn[512 + idx] = ss;
      p.bn[1536 + idx] = p.sb[idx] - p.smean[idx] * ss;
    }
    float os = p.og[c] / sqrtf(p.ov[c] + 1e-5f);
    p.bn[2560 + c] = os;
    p.bn[2816 + c] = p.ob[c] - p.om[c] * os + p.conv_ob[c] * os + p.mbias[c];
  }
}

// ------------------------------------------------------- small kernels ------
// [B][C][S] f32 -> [B][S][C] bf16
__global__ __launch_bounds__(256) void tposeb_k(const float* src, short* dst) {
  __shared__ float tile[32][33];
  int pc = blockIdx.x, cc = blockIdx.y, b = blockIdx.z;
  int tx = threadIdx.x & 31, ty = threadIdx.x >> 5;
  const float* s = src + ((size_t)b * 256 + cc * 32) * 1024 + pc * 32;
#pragma unroll
  for (int k = 0; k < 4; ++k)
    tile[ty + 8 * k][tx] = s[(ty + 8 * k) * 1024 + tx];
  __syncthreads();
  short* d = dst + ((size_t)b * 1024 + pc * 32) * 256 + cc * 32;
#pragma unroll
  for (int k = 0; k < 4; ++k)
    d[(ty + 8 * k) * 256 + tx] = f2bf(tile[tx][ty + 8 * k]);
}

__global__ __launch_bounds__(256) void camean_k(const float* x, float* partial) {
  int blk = blockIdx.x, c = threadIdx.x;
  const float* px = x + ((size_t)blk * 64) * 256 + c;
  float s = 0.f;
#pragma unroll 4
  for (int r = 0; r < 64; ++r) s += px[(size_t)r * 256];
  partial[blk * 256 + c] = s;
}

__global__ __launch_bounds__(256) void ca2_k(const float* partial, const float* w1,
                                             const float* w2, float* y2) {
  __shared__ float ly[256];
  __shared__ float ly1[16];
  int b = blockIdx.x, c = threadIdx.x;
  float s = 0.f;
#pragma unroll
  for (int j = 0; j < 16; ++j) s += partial[(b * 16 + j) * 256 + c];
  ly[c] = s * (1.f / 1024.f);
  __syncthreads();
  if (c < 16) {
    float a = 0.f;
    const float* wp = w1 + c * 256;
    for (int i = 0; i < 256; ++i) a += ly[i] * wp[i];
    ly1[c] = fmaxf(a, 0.f);
  }
  __syncthreads();
  float a = 0.f;
  const float* wp = w2 + c * 16;
#pragma unroll
  for (int j = 0; j < 16; ++j) a += ly1[j] * wp[j];
  y2[b * 256 + c] = 1.f / (1.f + __expf(-a));
}

__global__ __launch_bounds__(256) void bm1_k(const float* paT, const float* xT,
                                             const float* y2, float* pa_ca) {
  __shared__ float sp[32][33], sx[32][33], so[32][33];
  __shared__ float rinv[32];
  int bc = blockIdx.x, t = threadIdx.x;
  for (int e = t; e < 1024; e += 256) {
    sp[e >> 5][e & 31] = paT[(size_t)bc * 1024 + e];
    sx[e >> 5][e & 31] = xT[(size_t)bc * 1024 + e];
  }
  __syncthreads();
  float yv = y2[bc];
  int i = t >> 3, j0 = (t & 7) * 4;
  float a0 = 0.f, a1 = 0.f, a2 = 0.f, a3 = 0.f;
  for (int k = 0; k < 32; ++k) {
    float pv = sp[i][k];
    a0 += pv * sx[k][j0];     a1 += pv * sx[k][j0 + 1];
    a2 += pv * sx[k][j0 + 2]; a3 += pv * sx[k][j0 + 3];
  }
  so[i][j0] = a0 * yv; so[i][j0 + 1] = a1 * yv;
  so[i][j0 + 2] = a2 * yv; so[i][j0 + 3] = a3 * yv;
  __syncthreads();
  if (t < 32) {
    float mx = -1e30f;
    for (int j = 0; j < 32; ++j) mx = fmaxf(mx, so[t][j]);
    float sum = 0.f;
    for (int j = 0; j < 32; ++j) { float pp = __expf(so[t][j] - mx); so[t][j] = pp; sum += pp; }
    rinv[t] = 1.f / sum;
  }
  __syncthreads();
  for (int e = t; e < 1024; e += 256)
    pa_ca[(size_t)bc * 1024 + e] = so[e >> 5][e & 31] * rinv[e >> 5];
}

__global__ __launch_bounds__(256) void bm2_k(const float* pa_ca, const float* saT, float* moT) {
  __shared__ float sp[32][33], ss[32][33];
  int bc = blockIdx.x, t = threadIdx.x;
  for (int e = t; e < 1024; e += 256) {
    sp[e >> 5][e & 31] = pa_ca[(size_t)bc * 1024 + e];
    ss[e >> 5][e & 31] = saT[(size_t)bc * 1024 + e];
  }
  __syncthreads();
  int i = t >> 3, j0 = (t & 7) * 4;
  float a0 = 0.f, a1 = 0.f, a2 = 0.f, a3 = 0.f;
  for (int k = 0; k < 32; ++k) {
    float pv = sp[i][k];
    a0 += pv * ss[k][j0];     a1 += pv * ss[k][j0 + 1];
    a2 += pv * ss[k][j0 + 2]; a3 += pv * ss[k][j0 + 3];
  }
  size_t base = (size_t)bc * 1024 + i * 32 + j0;
  moT[base] = a0; moT[base + 1] = a1; moT[base + 2] = a2; moT[base + 3] = a3;
}

template<int DUAL>
__global__ __launch_bounds__(256) void ln_k(const float* in, const float* res,
                                            const float* g, const float* bta,
                                            float* out, short* outB) {
  __shared__ float red[8];
  size_t row = blockIdx.x;
  int c = threadIdx.x;
  int wv = c >> 6, lane = c & 63;
  float v = in[row * 256 + c] + res[row * 256 + c];
  float s = v;
  for (int mk = 1; mk < 64; mk <<= 1) s += __shfl_xor(s, mk);
  if (lane == 0) red[wv] = s;
  __syncthreads();
  float mu = (red[0] + red[1] + red[2] + red[3]) * (1.f / 256.f);
  float d = v - mu;
  float q = d * d;
  for (int mk = 1; mk < 64; mk <<= 1) q += __shfl_xor(q, mk);
  if (lane == 0) red[4 + wv] = q;
  __syncthreads();
  float var = (red[4] + red[5] + red[6] + red[7]) * (1.f / 256.f);
  float o = d * rsqrtf(var + 1e-5f) * g[c] + bta[c];
  out[row * 256 + c] = o;
  if (DUAL) outB[row * 256 + c] = f2bf(o);
}

// ---------------------------------------------------------------- host ------
extern "C" void kernel_launch(void* const* d_in, const int* in_sizes, int n_in,
                              void* d_out, int out_size, void* d_ws, size_t ws_size,
                              hipStream_t stream) {
  (void)in_sizes; (void)n_in; (void)out_size; (void)ws_size;
  const float* value    = (const float*)d_in[0];
  const float* key      = (const float*)d_in[1];
  const float* query    = (const float*)d_in[2];
  const float* res      = (const float*)d_in[3];
  const float* attn_wi  = (const float*)d_in[4];
  const float* attn_bi  = (const float*)d_in[5];
  const float* attn_wo  = (const float*)d_in[6];
  const float* attn_bo  = (const float*)d_in[7];
  const float* mod_bias = (const float*)d_in[8];
  const float* ca_w1    = (const float*)d_in[9];
  const float* ca_w2    = (const float*)d_in[10];
  const float* pa_w     = (const float*)d_in[11];
  const float* pa_bn_g  = (const float*)d_in[12];
  const float* pa_bn_b  = (const float*)d_in[13];
  const float* pa_bn_m  = (const float*)d_in[14];
  const float* pa_bn_v  = (const float*)d_in[15];
  const float* sa_w     = (const float*)d_in[16];
  const float* sa_b     = (const float*)d_in[17];
  const float* sa_bn_g  = (const float*)d_in[18];
  const float* sa_bn_b  = (const float*)d_in[19];
  const float* sa_bn_m  = (const float*)d_in[20];
  const float* sa_bn_v  = (const float*)d_in[21];
  const float* sa_out_w = (const float*)d_in[22];
  const float* sa_out_b = (const float*)d_in[23];
  const float* out_w    = (const float*)d_in[24];
  const float* out_b    = (const float*)d_in[25];
  const float* out_bn_g = (const float*)d_in[26];
  const float* out_bn_b = (const float*)d_in[27];
  const float* out_bn_m = (const float*)d_in[28];
  const float* out_bn_v = (const float*)d_in[29];
  const float* ln1_g    = (const float*)d_in[30];
  const float* ln1_b    = (const float*)d_in[31];
  const float* ln2_g    = (const float*)d_in[32];
  const float* ln2_b    = (const float*)d_in[33];
  const float* mlp_w1   = (const float*)d_in[34];
  const float* mlp_b1   = (const float*)d_in[35];
  const float* dw_w     = (const float*)d_in[36];
  const float* dw_b     = (const float*)d_in[37];
  const float* pw_w     = (const float*)d_in[38];
  const float* pw_b     = (const float*)d_in[39];
  const float* mlp_w2   = (const float*)d_in[40];
  const float* mlp_b2   = (const float*)d_in[41];

  char* ws = (char*)d_ws;
  const size_t MB = 1024 * 1024;
  char* A = ws + 0 * MB;     // 16MB: vkq | xT+paT | saCat | h | h2
  char* Bx = ws + 16 * MB;   // 16MB: qkv | pa_ca | hc1
  char* Cx = ws + 32 * MB;   // 8MB:  ctxB | saT | modB | ffBuf
  float* xbuf  = (float*)(ws + 40 * MB);
  short* xbf   = (short*)(ws + 48 * MB);
  char* Fx = ws + 52 * MB;   // 8MB: moT | synBuf
  float* q2buf = (float*)(ws + 60 * MB);
  short* q2B   = (short*)(ws + 68 * MB);
  short* wdw   = (short*)(ws + 72 * MB);
  short* wpw   = (short*)(ws + 90 * MB);
  size_t o = 108 * MB;
  short* w_awi  = (short*)(ws + o); o += 768 * 256 * 2;
  short* w_awo  = (short*)(ws + o); o += 256 * 256 * 2;
  short* w_pa   = (short*)(ws + o); o += 256 * 256 * 2;
  short* w_sa   = (short*)(ws + o); o += (size_t)4 * 9 * 256 * 256 * 2;
  short* w_saou = (short*)(ws + o); o += 256 * 1024 * 2;
  short* w_out  = (short*)(ws + o); o += 256 * 256 * 2;
  short* w_mlp1 = (short*)(ws + o); o += 1024 * 256 * 2;
  short* w_mlp2 = (short*)(ws + o); o += 256 * 1024 * 2;
  float* bn     = (float*)(ws + o); o += 3072 * 4;
  float* y2buf  = (float*)(ws + o); o += 8 * 256 * 4;
  float* capart = (float*)(ws + o); o += 128 * 256 * 4;
  short* zbuf   = (short*)(ws + o); o += 2048 * 2;

  short* vkq  = (short*)A;
  short* qkv  = (short*)Bx;
  short* ctxB = (short*)Cx;
  float* xT   = (float*)A;
  float* paT  = (float*)(A + 8 * MB);
  float* pa_ca = (float*)Bx;
  short* saCat = (short*)A;
  float* saT  = (float*)Cx;
  float* moT  = (float*)Fx;
  short* modB = (short*)Cx;
  float* synBuf = (float*)Fx;
  short* hB   = (short*)A;
  short* hc1B = (short*)Bx;
  short* h2B  = (short*)A;
  float* ffBuf = (float*)Cx;

  const int LDSB = 2 * 16384 * 2;   // 64KB dynamic (full gemmd)
  const int LDSH = 2 * 8192 * 2;    // 32KB dynamic (HALF gemmd)
  const int LDSC = 40960 * 2;       // 80KB dynamic (convh r9)
  hipFuncSetAttribute((const void*)gemmd_k<1, 1, 1, 0, 1>, hipFuncAttributeMaxDynamicSharedMemorySize, LDSH);
  hipFuncSetAttribute((const void*)gemmd_k<1, 1, 2, 1, 1>, hipFuncAttributeMaxDynamicSharedMemorySize, LDSH);
  hipFuncSetAttribute((const void*)gemmd_k<1, 4, 3, 1, 1>, hipFuncAttributeMaxDynamicSharedMemorySize, LDSH);
  hipFuncSetAttribute((const void*)gemmd_k<9, 3, 1, 0, 0>, hipFuncAttributeMaxDynamicSharedMemorySize, LDSB);
  hipFuncSetAttribute((const void*)gemmd_k<1, 1, 3, 1, 1>, hipFuncAttributeMaxDynamicSharedMemorySize, LDSH);
  hipFuncSetAttribute((const void*)gemmd_k<1, 5, 0, 0, 1>, hipFuncAttributeMaxDynamicSharedMemorySize, LDSH);
  hipFuncSetAttribute((const void*)gemmd_k<1, 2, 1, 0, 0>, hipFuncAttributeMaxDynamicSharedMemorySize, LDSB);
  hipFuncSetAttribute((const void*)gemmd_k<1, 1, 0, 0, 1>, hipFuncAttributeMaxDynamicSharedMemorySize, LDSH);
  hipFuncSetAttribute((const void*)convh_k, hipFuncAttributeMaxDynamicSharedMemorySize, LDSC);

  // ---- fused prep (1 launch instead of 18) ----
  PP pp;
  pp.value = value; pp.key = key; pp.query = query;
  pp.attn_wi = attn_wi; pp.attn_wo = attn_wo; pp.pa_w = pa_w;
  pp.sa_out_w = sa_out_w; pp.out_w = out_w; pp.mlp_w1 = mlp_w1; pp.mlp_w2 = mlp_w2;
  pp.sa_w = sa_w; pp.dw_w = dw_w; pp.pw_w = pw_w;
  pp.vkq = vkq; pp.w_awi = w_awi; pp.w_awo = w_awo; pp.w_pa = w_pa;
  pp.w_saou = w_saou; pp.w_out = w_out; pp.w_mlp1 = w_mlp1; pp.w_mlp2 = w_mlp2;
  pp.w_sa = w_sa; pp.wdw = wdw; pp.wpw = wpw; pp.zbuf = zbuf;
  pp.pg = pa_bn_g; pp.pb = pa_bn_b; pp.pm = pa_bn_m; pp.pv = pa_bn_v;
  pp.sg = sa_bn_g; pp.sb = sa_bn_b; pp.smean = sa_bn_m; pp.svar = sa_bn_v;
  pp.og = out_bn_g; pp.ob = out_bn_b; pp.om = out_bn_m; pp.ov = out_bn_v;
  pp.conv_ob = out_b; pp.mbias = mod_bias; pp.bn = bn;
  prep_k<<<16514, 256, 0, stream>>>(pp);

  GP g;
  g.zero = zbuf; g.scale = nullptr; g.shift = nullptr; g.aux = nullptr;
  g.aZStride = 0; g.wZStride = 0; g.oZStride = 0;
  g.outColOff = 0; g.outZOff = 0;
  g.dil0 = 1; g.dil1 = 1; g.dil2 = 1; g.dil3 = 1;
  g.outF = nullptr; g.outB = nullptr; g.outT = nullptr;

  // ---- QKV (z=0,1,2) ----
  g.A = vkq; g.W = w_awi; g.outB = qkv; g.bias = attn_bi;
  g.N = 256; g.Kc = 256; g.ldA = 256; g.ldOut = 256; g.T = 4; g.nkcs = 2;
  g.aZStride = (size_t)MM * 256; g.wZStride = 256 * 256; g.oZStride = (size_t)MM * 256;
  gemmd_k<1, 1, 1, 0, 1><<<dim3(512, 1, 3), 256, LDSH, stream>>>(g);
  g.aZStride = 0; g.wZStride = 0; g.oZStride = 0;

  // ---- attention ----
  attn_k<<<dim3(16, 64), 256, 0, stream>>>(qkv, qkv + (size_t)MM * 256,
                                           qkv + (size_t)2 * MM * 256, ctxB);

  // ---- out-proj -> xbuf(f32) + xbf(bf16) + xT(f32 transposed) ----
  g.A = ctxB; g.W = w_awo; g.outF = xbuf; g.outB = xbf; g.outT = xT; g.bias = attn_bo;
  gemmd_k<1, 1, 2, 1, 1><<<dim3(512), 256, LDSH, stream>>>(g);

  // ---- pa = x * sigmoid(BN(x @ pa_w^T)) -> paT (transposed only) ----
  g.A = xbf; g.W = w_pa; g.outF = nullptr; g.outB = nullptr; g.outT = paT; g.bias = nullptr;
  g.scale = bn; g.shift = bn + 256; g.aux = xbuf;
  gemmd_k<1, 4, 3, 1, 1><<<dim3(512), 256, LDSH, stream>>>(g);
  g.scale = nullptr; g.shift = nullptr; g.aux = nullptr;

  // ---- channel attention + pa@ca softmax ----
  camean_k<<<128, 256, 0, stream>>>(xbuf, capart);
  ca2_k<<<8, 256, 0, stream>>>(capart, ca_w1, ca_w2, y2buf);
  bm1_k<<<2048, 256, 0, stream>>>(paT, xT, y2buf, pa_ca);

  // ---- 4 dilated 3x3 convs (z-batched) -> saCat bf16 [M,1024] ----
  g.A = xbf; g.W = w_sa; g.outB = saCat; g.outF = nullptr; g.outT = nullptr;
  g.bias = sa_b; g.scale = bn + 512; g.shift = bn + 1536;
  g.ldOut = 1024; g.outZOff = 256; g.wZStride = (size_t)9 * 256 * 256;
  g.dil0 = 1; g.dil1 = 6; g.dil2 = 12; g.dil3 = 18;
  g.T = 36; g.nkcs = 2;
  gemmd_k<9, 3, 1, 0, 0><<<dim3(128, 1, 4), 256, LDSB, stream>>>(g);
  g.outZOff = 0; g.wZStride = 0; g.scale = nullptr; g.shift = nullptr;
  g.dil0 = 1; g.dil1 = 1; g.dil2 = 1; g.dil3 = 1;

  // ---- sa = saCat @ sa_out_w^T + b -> saT (transposed only) ----
  g.A = saCat; g.W = w_saou; g.outB = nullptr; g.outT = saT; g.bias = sa_out_b;
  g.N = 256; g.Kc = 1024; g.ldA = 1024; g.ldOut = 256; g.T = 16; g.nkcs = 4;
  gemmd_k<1, 1, 3, 1, 1><<<dim3(512), 256, LDSH, stream>>>(g);

  // ---- mod_out = pa_ca @ sa ----
  bm2_k<<<2048, 256, 0, stream>>>(pa_ca, saT, moT);
  tposeb_k<<<dim3(32, 8, 8), 256, 0, stream>>>(moT, modB);

  // ---- syn = BN(mod_out @ out_w^T + out_b) + mod_bias + x ----
  g.A = modB; g.W = w_out; g.outF = synBuf; g.outT = nullptr; g.bias = nullptr;
  g.scale = bn + 2560; g.shift = bn + 2816; g.aux = xbuf;
  g.N = 256; g.Kc = 256; g.ldA = 256; g.ldOut = 256; g.T = 4; g.nkcs = 2;
  gemmd_k<1, 5, 0, 0, 1><<<dim3(512), 256, LDSH, stream>>>(g);
  g.scale = nullptr; g.shift = nullptr; g.aux = nullptr;

  // ---- q2 = LN(syn + res) ----
  ln_k<1><<<8192, 256, 0, stream>>>(synBuf, res, ln1_g, ln1_b, q2buf, q2B);

  // ---- h = gelu(q2 @ mlp_w1^T + b1) ----
  g.A = q2B; g.W = w_mlp1; g.outB = hB; g.outF = nullptr; g.bias = mlp_b1;
  g.N = 1024; g.Kc = 256; g.ldA = 256; g.ldOut = 1024; g.T = 4; g.nkcs = 2;
  gemmd_k<1, 2, 1, 0, 0><<<dim3(512), 256, LDSB, stream>>>(g);

  // ---- hc1 = conv3x3(h, dw_w) + dw_b ----
  convh_k<<<dim3(512), 256, LDSC, stream>>>(hB, wdw, hc1B, dw_b);

  // ---- h2 = conv3x3(hc1, pw_w) + pw_b ----
  convh_k<<<dim3(512), 256, LDSC, stream>>>(hc1B, wpw, h2B, pw_b);

  // ---- ff = h2 @ mlp_w2^T + b2 ----
  g.A = h2B; g.W = w_mlp2; g.outF = ffBuf; g.outB = nullptr; g.bias = mlp_b2;
  g.N = 256; g.Kc = 1024; g.ldA = 1024; g.ldOut = 256; g.T = 16; g.nkcs = 4;
  gemmd_k<1, 1, 0, 0, 1><<<dim3(512), 256, LDSH, stream>>>(g);

  // ---- out = LN(ff + q2) ----
  ln_k<0><<<8192, 256, 0, stream>>>(ffBuf, q2buf, ln2_g, ln2_b, (float*)d_out, nullptr);
}